// Round 1
// baseline (236.700 us; speedup 1.0000x reference)
//
#include <hip/hip_runtime.h>
#include <hip/hip_bf16.h>

#define S_LEN 2048
#define NH    16
#define HD    64
#define HID   1024
#define BATCH 2
#define STK   72   // kt/vt LDS stride in shorts (144B rows, 16B aligned)

typedef __bf16 bf16x8 __attribute__((ext_vector_type(8)));
typedef float  f32x4  __attribute__((ext_vector_type(4)));

__device__ __forceinline__ unsigned int pk2(float lo, float hi) {
    union { __hip_bfloat162 h; unsigned int u; } c;
    c.h = __float22bfloat162_rn(make_float2(lo, hi));   // v_cvt_pk_bf16_f32
    return c.u;
}
__device__ __forceinline__ uint4 pk8(float4 a, float4 b) {
    uint4 o;
    o.x = pk2(a.x, a.y); o.y = pk2(a.z, a.w);
    o.z = pk2(b.x, b.y); o.w = pk2(b.z, b.w);
    return o;
}
__device__ __forceinline__ float exp2_hw(float x) {
    float r; asm("v_exp_f32 %0, %1" : "=v"(r) : "v"(x)); return r;
}
__device__ __forceinline__ void gll16(const unsigned short* g, unsigned short* l) {
    __builtin_amdgcn_global_load_lds(
        (const __attribute__((address_space(1))) void*)g,
        (__attribute__((address_space(3))) void*)l, 16, 0, 0);
}

__global__ __launch_bounds__(256)
void fill_constf(float* __restrict__ out, long n, float v) {
    long i = (long)blockIdx.x * 256 + threadIdx.x;
    const long stride = (long)gridDim.x * 256;
    for (; i < n; i += stride) out[i] = v;
}

// fp32 -> bf16 bulk convert, 8 elems/iter.
__global__ __launch_bounds__(256)
void cvt_bf16(const float* __restrict__ src, unsigned short* __restrict__ dst, long n8) {
    long t = (long)blockIdx.x * 256 + threadIdx.x;
    const long stride = (long)gridDim.x * 256;
    for (; t < n8; t += stride) {
        const float4 a = *(const float4*)(src + t * 8);
        const float4 b = *(const float4*)(src + t * 8 + 4);
        *(uint4*)(dst + t * 8) = pk8(a, b);
    }
}
// two-tensor variant (x and qkv_w in one launch)
__global__ __launch_bounds__(256)
void cvt2_bf16(const float* __restrict__ s0, unsigned short* __restrict__ d0, long n0,
               const float* __restrict__ s1, unsigned short* __restrict__ d1, long n1) {
    long t = (long)blockIdx.x * 256 + threadIdx.x;
    const long stride = (long)gridDim.x * 256;
    for (; t < n0 + n1; t += stride) {
        const float* s; unsigned short* d; long i;
        if (t < n0) { s = s0; d = d0; i = t; } else { s = s1; d = d1; i = t - n0; }
        const float4 a = *(const float4*)(s + i * 8);
        const float4 b = *(const float4*)(s + i * 8 + 4);
        *(uint4*)(d + i * 8) = pk8(a, b);
    }
}

// C = A[M,K]·W[N,K]^T + bias, bf16 in, global_load_lds staging.
// Depth-2 software pipeline: 3 LDS buffer sets, counted s_waitcnt vmcnt(4),
// one raw s_barrier per K-step (prefetch loads stay in flight across it).
// LDS tile is chunk-XOR swizzled (c_lin = c ^ ((row>>1)&3)) via pre-swizzled
// GLOBAL source addresses (gll dest must stay linear) + swizzled ds_read —
// makes the 8 fragment ds_read_b128 per K-step bank-conflict-free.
// mode 0: scatter bf16 -> q/k (row-scatter) and V^T (packed 8B); mode 1: fp32 store.
__global__ __launch_bounds__(256)
void gemm_bf16(const unsigned short* __restrict__ A,
               const unsigned short* __restrict__ W,
               const float* __restrict__ bias,
               unsigned short* __restrict__ o0,
               unsigned short* __restrict__ o1,
               unsigned short* __restrict__ o2,
               float* __restrict__ of,
               int mode)
{
    __shared__ __align__(16) unsigned short lA[3][128 * 32];
    __shared__ __align__(16) unsigned short lB[3][128 * 32];
    const int tid  = threadIdx.x;
    const int lane = tid & 63, wv = tid >> 6;
    const int quad = lane >> 4, l16 = lane & 15;
    const int wm = (wv & 1) * 64, wn = (wv >> 1) * 64;

    // bijective XCD-aware block swizzle (m204): same-XCD blocks get a
    // contiguous slab of tiles -> A-row / B-panel L2 reuse.
    const int nwg = gridDim.x * gridDim.y;
    const int bid = blockIdx.y * gridDim.x + blockIdx.x;
    const int xcd = bid & 7, boff = bid >> 3;
    const int qd = nwg >> 3, rm = nwg & 7;
    const int swz = (xcd < rm ? xcd * (qd + 1) : rm * (qd + 1) + (xcd - rm) * qd) + boff;
    const int m0 = (swz / gridDim.x) * 128, n0 = (swz % gridDim.x) * 128;

    f32x4 acc[4][4] = {};

    // staging geometry: wave wv covers rows [wv*32, wv*32+32) in two 16-row
    // halves; lane l -> row wv*32 + (l>>2), linear chunk c_lin = l&3.
    // Source chunk is pre-swizzled: c_src = c_lin ^ ((row>>1)&3) = (l&3)^((l>>3)&3).
    const int srow0 = wv * 32 + (lane >> 2);
    const int srow1 = srow0 + 16;
    const int csrc  = ((lane & 3) ^ ((lane >> 3) & 3)) * 8;
    const unsigned short* pa0 = A + (long)(m0 + srow0) * HID + csrc;
    const unsigned short* pa1 = A + (long)(m0 + srow1) * HID + csrc;
    const unsigned short* pb0 = W + (long)(n0 + srow0) * HID + csrc;
    const unsigned short* pb1 = W + (long)(n0 + srow1) * HID + csrc;

    // fragment read chunk: data chunk `quad` of row r sits at c_lin = quad ^ ((r>>1)&3);
    // for rows wm+mt*16+l16 that is quad ^ ((l16>>1)&3) -- per-lane constant.
    const int cq8 = (quad ^ ((l16 >> 1) & 3)) * 8;

#define STAGE_G(bufi, koff)                                        \
    do {                                                           \
        gll16(pa0 + (koff), &lA[bufi][(wv * 2 + 0) * 512]);        \
        gll16(pa1 + (koff), &lA[bufi][(wv * 2 + 1) * 512]);        \
        gll16(pb0 + (koff), &lB[bufi][(wv * 2 + 0) * 512]);        \
        gll16(pb1 + (koff), &lB[bufi][(wv * 2 + 1) * 512]);        \
    } while (0)

    // prologue: tiles 0 and 1 in flight (8 outstanding vmem per wave)
    STAGE_G(0, 0);
    STAGE_G(1, 32);

    int cur = 0;
    for (int k0 = 0; k0 < HID; k0 += 32) {
        // wait tile k (leave tile k+1's 4 loads in flight); last iter drains.
        if (k0 + 32 < HID) { asm volatile("s_waitcnt vmcnt(4)" ::: "memory"); }
        else               { asm volatile("s_waitcnt vmcnt(0)" ::: "memory"); }
        __builtin_amdgcn_s_barrier();
        asm volatile("" ::: "memory");

        if (k0 + 64 < HID) {
            const int nxt = cur ? cur - 1 : 2;       // (cur+2) mod 3
            STAGE_G(nxt, k0 + 64);
        }

        bf16x8 af[4], bfr[4];
#pragma unroll
        for (int mt = 0; mt < 4; mt++)
            af[mt] = *(const bf16x8*)&lA[cur][(wm + mt * 16 + l16) * 32 + cq8];
#pragma unroll
        for (int nt = 0; nt < 4; nt++)
            bfr[nt] = *(const bf16x8*)&lB[cur][(wn + nt * 16 + l16) * 32 + cq8];
#pragma unroll
        for (int mt = 0; mt < 4; mt++)
#pragma unroll
            for (int nt = 0; nt < 4; nt++)
                acc[mt][nt] = __builtin_amdgcn_mfma_f32_16x16x32_bf16(
                    af[mt], bfr[nt], acc[mt][nt], 0, 0, 0);

        cur = (cur < 2) ? cur + 1 : 0;
    }
#undef STAGE_G

    if (mode == 0) {
#pragma unroll
        for (int nt = 0; nt < 4; nt++) {
            const int n = n0 + wn + nt * 16 + l16;
            const float bv = bias[n];
            const int part = n >> 10, f = n & 1023, h = f >> 6, d = f & 63;
#pragma unroll
            for (int mt = 0; mt < 4; mt++) {
                const int mbase = m0 + wm + mt * 16 + quad * 4;
                const int b = mbase >> 11, s0 = mbase & 2047;
                const int bh = b * NH + h;
                if (part == 2) {
                    // V^T: 4 consecutive s per lane -> one packed 8B store
                    uint2 o;
                    o.x = pk2(acc[mt][nt][0] + bv, acc[mt][nt][1] + bv);
                    o.y = pk2(acc[mt][nt][2] + bv, acc[mt][nt][3] + bv);
                    *(uint2*)&o2[((long)bh * HD + d) * S_LEN + s0] = o;
                } else {
                    unsigned short* dst = (part == 0) ? o0 : o1;
#pragma unroll
                    for (int r = 0; r < 4; r++) {
                        union { __hip_bfloat16 h; unsigned short u; } cv;
                        cv.h = __float2bfloat16(acc[mt][nt][r] + bv);
                        dst[((long)bh * S_LEN + s0 + r) * HD + d] = cv.u;
                    }
                }
            }
        }
    } else {
#pragma unroll
        for (int nt = 0; nt < 4; nt++) {
            const int n = n0 + wn + nt * 16 + l16;
            const float bv = bias[n];
#pragma unroll
            for (int mt = 0; mt < 4; mt++) {
                const int mbase = m0 + wm + mt * 16 + quad * 4;
#pragma unroll
                for (int r = 0; r < 4; r++)
                    of[(long)(mbase + r) * HID + n] = acc[mt][nt][r] + bv;
            }
        }
    }
}

// Flash attention, S^T form, exp2 softmax. 512 threads (8 waves), q-tile 128.
// Register-prefetch double-buffered K/V staging; 2 barriers per 64-key tile.
__global__ __launch_bounds__(512)
void attn(const unsigned short* __restrict__ q,
          const unsigned short* __restrict__ k,
          const unsigned short* __restrict__ vt_g,   // [b,h,64,S]
          const int* __restrict__ mask,
          unsigned short* __restrict__ ctx)          // [b,S,1024] bf16
{
    __shared__ __align__(16) unsigned short kt[64 * STK];
    __shared__ __align__(16) unsigned short vt[64 * STK];
    __shared__ __align__(16) __bf16 pt[8][16 * 72];
    __shared__ float mkv[64];

    const int tid  = threadIdx.x;
    const int lane = tid & 63, wv = tid >> 6;          // wv 0..7
    const int quad = lane >> 4, l16 = lane & 15;
    const int qt = blockIdx.x, h = blockIdx.y, b = blockIdx.z;
    const int bh = b * NH + h;
    const float SC = 0.18033688f;   // 0.125 * log2(e)

    const int sq = qt * 128 + wv * 16 + l16;
    bf16x8 qf0 = *(const bf16x8*)&q[((long)bh * S_LEN + sq) * HD + quad * 8];
    bf16x8 qf1 = *(const bf16x8*)&q[((long)bh * S_LEN + sq) * HD + 32 + quad * 8];

    float mrun = -1e30f, lrun = 0.f;
    f32x4 Of[4] = {};

    // staging: 512 threads cover 64 rows x 8 chunks, one uint4 each per matrix
    const int sr = tid >> 3, sc8 = (tid & 7) * 8;
    const unsigned short* kg = k    + ((long)bh * S_LEN + sr) * HD + sc8;
    const unsigned short* vg = vt_g + ((long)bh * HD + sr) * S_LEN + sc8;
    __bf16* ptw = pt[wv];

    // prefetch tile 0
    uint4 rk = *(const uint4*)(kg);
    uint4 rv = *(const uint4*)(vg);
    float rm = 0.f;
    if (tid < 64) rm = (mask[b * S_LEN + tid] == 0) ? -1e9f : 0.f;

    for (int k0 = 0; k0 < S_LEN; k0 += 64) {
        *(uint4*)&kt[sr * STK + sc8] = rk;
        *(uint4*)&vt[sr * STK + sc8] = rv;
        if (tid < 64) mkv[tid] = rm;
        if (k0 + 64 < S_LEN) {
            rk = *(const uint4*)(kg + (long)(k0 + 64) * HD);
            rv = *(const uint4*)(vg + (k0 + 64));
            if (tid < 64) rm = (mask[b * S_LEN + k0 + 64 + tid] == 0) ? -1e9f : 0.f;
        }
        __syncthreads();

        float st[4][4];
#pragma unroll
        for (int nt = 0; nt < 4; nt++) {
            bf16x8 k0f = *(const bf16x8*)&kt[(nt * 16 + l16) * STK + quad * 8];
            bf16x8 k1f = *(const bf16x8*)&kt[(nt * 16 + l16) * STK + 32 + quad * 8];
            f32x4 s = {};
            s = __builtin_amdgcn_mfma_f32_16x16x32_bf16(k0f, qf0, s, 0, 0, 0);
            s = __builtin_amdgcn_mfma_f32_16x16x32_bf16(k1f, qf1, s, 0, 0, 0);
            const float4 mv = *(const float4*)&mkv[nt * 16 + quad * 4];
#pragma unroll
            for (int r = 0; r < 4; r++) st[nt][r] = fmaf(s[r], SC, (&mv.x)[r]);
        }

        float mx = st[0][0];
#pragma unroll
        for (int nt = 0; nt < 4; nt++)
#pragma unroll
            for (int r = 0; r < 4; r++) mx = fmaxf(mx, st[nt][r]);
        mx = fmaxf(mx, __shfl_xor(mx, 16, 64));
        mx = fmaxf(mx, __shfl_xor(mx, 32, 64));
        const float mn = fmaxf(mrun, mx);
        const float alpha = exp2_hw(mrun - mn);
        float pr[4][4];
#pragma unroll
        for (int nt = 0; nt < 4; nt++)
#pragma unroll
            for (int r = 0; r < 4; r++) pr[nt][r] = exp2_hw(st[nt][r] - mn);
        float rs = 0.f;
#pragma unroll
        for (int nt = 0; nt < 4; nt++)
#pragma unroll
            for (int r = 0; r < 4; r++) rs += pr[nt][r];
        rs += __shfl_xor(rs, 16, 64);
        rs += __shfl_xor(rs, 32, 64);
        lrun = lrun * alpha + rs;
        mrun = mn;

#pragma unroll
        for (int nt = 0; nt < 4; nt++) {
            const unsigned long long lo = pk2(pr[nt][0], pr[nt][1]);
            const unsigned long long hi = pk2(pr[nt][2], pr[nt][3]);
            *(unsigned long long*)&ptw[l16 * 72 + nt * 16 + quad * 4] = lo | (hi << 32);
        }
        asm volatile("" ::: "memory");

#pragma unroll
        for (int nt = 0; nt < 4; nt++) Of[nt] *= alpha;

#pragma unroll
        for (int ks = 0; ks < 2; ks++) {
            bf16x8 bp = *(const bf16x8*)&ptw[l16 * 72 + ks * 32 + quad * 8];
#pragma unroll
            for (int nt = 0; nt < 4; nt++) {
                bf16x8 av = *(const bf16x8*)&vt[(nt * 16 + l16) * STK + ks * 32 + quad * 8];
                Of[nt] = __builtin_amdgcn_mfma_f32_16x16x32_bf16(av, bp, Of[nt], 0, 0, 0);
            }
        }
        __syncthreads();
    }

    const float inv = 1.f / lrun;
#pragma unroll
    for (int nt = 0; nt < 4; nt++) {
        uint2 o;
        o.x = pk2(Of[nt][0] * inv, Of[nt][1] * inv);
        o.y = pk2(Of[nt][2] * inv, Of[nt][3] * inv);
        *(uint2*)&ctx[((long)b * S_LEN + sq) * HID + h * HD + nt * 16 + quad * 4] = o;
    }
}

extern "C" void kernel_launch(void* const* d_in, const int* in_sizes, int n_in,
                              void* d_out, int out_size, void* d_ws, size_t ws_size,
                              hipStream_t stream) {
    float* outp = (float*)d_out;

    const float* x = nullptr; const int* mask = nullptr;
    const float* qkv_w = nullptr; const float* qkv_b = nullptr;
    const float* out_w = nullptr; const float* out_b = nullptr;
    for (int i = 0; i < n_in; i++) {
        switch (in_sizes[i]) {
            case 4194304: x     = (const float*)d_in[i]; break;
            case 4096:    mask  = (const int*)d_in[i];   break;
            case 3145728: qkv_w = (const float*)d_in[i]; break;
            case 3072:    qkv_b = (const float*)d_in[i]; break;
            case 1048576: out_w = (const float*)d_in[i]; break;
            case 1024:    out_b = (const float*)d_in[i]; break;
            default: break;
        }
    }
    if (!x || !mask || !qkv_w || !qkv_b || !out_w || !out_b) {
        fill_constf<<<256, 256, 0, stream>>>(outp, (long)out_size, 1000.0f);
        return;
    }

    const size_t per = (size_t)BATCH * NH * S_LEN * HD;   // 4,194,304
    const size_t nx  = (size_t)BATCH * S_LEN * HID;
    const size_t nqw = (size_t)3 * HID * HID;
    const size_t now = (size_t)HID * HID;
    if (ws_size < 4 * per * sizeof(unsigned short)) {
        fill_constf<<<256, 256, 0, stream>>>(outp, (long)out_size, 2000.0f);
        return;
    }

    // Aliasing discipline (no buffer read+written in the same kernel):
    //   xb  = wsc : dead after gemm1; attn overwrites with ctx
    //   qwb = d_out[0,6.3MB) : dead after gemm1; gemm2 overwrites with output
    //   owb = wsq : written AFTER attn (q dead), read only by gemm2
    unsigned short* wsq = (unsigned short*)d_ws;
    unsigned short* wsk = wsq + per;
    unsigned short* wsv = wsk + per;               // V^T [b,h,64,S]
    unsigned short* wsc = wsv + per;               // phase 1: xb; phase 2: ctx
    unsigned short* xb  = wsc;
    unsigned short* qwb = (unsigned short*)d_out;
    unsigned short* owb = wsq;

    cvt2_bf16<<<1024, 256, 0, stream>>>(x, xb, (long)(nx / 8), qkv_w, qwb, (long)(nqw / 8));
    gemm_bf16<<<dim3(3 * HID / 128, BATCH * S_LEN / 128), 256, 0, stream>>>(
        xb, qwb, qkv_b, wsq, wsk, wsv, nullptr, 0);
    attn<<<dim3(S_LEN / 128, NH, BATCH), 512, 0, stream>>>(wsq, wsk, wsv, mask, wsc);
    cvt_bf16<<<512, 256, 0, stream>>>(out_w, owb, (long)(now / 8));
    gemm_bf16<<<dim3(HID / 128, BATCH * S_LEN / 128), 256, 0, stream>>>(
        wsc, owb, out_b, nullptr, nullptr, nullptr, outp, 1);
}

// Round 2
// 231.440 us; speedup vs baseline: 1.0227x; 1.0227x over previous
//
#include <hip/hip_runtime.h>
#include <hip/hip_bf16.h>

#define S_LEN 2048
#define NH    16
#define HD    64
#define HID   1024
#define BATCH 2
#define STK   72   // kt/vt LDS stride in shorts (144B rows, 16B aligned)
#define SCQ   0.18033688f   // 0.125 * log2(e), folded into q in gemm1 epilogue

typedef __bf16 bf16x8 __attribute__((ext_vector_type(8)));
typedef float  f32x4  __attribute__((ext_vector_type(4)));

__device__ __forceinline__ unsigned int pk2(float lo, float hi) {
    union { __hip_bfloat162 h; unsigned int u; } c;
    c.h = __float22bfloat162_rn(make_float2(lo, hi));   // v_cvt_pk_bf16_f32
    return c.u;
}
__device__ __forceinline__ uint4 pk8(float4 a, float4 b) {
    uint4 o;
    o.x = pk2(a.x, a.y); o.y = pk2(a.z, a.w);
    o.z = pk2(b.x, b.y); o.w = pk2(b.z, b.w);
    return o;
}
__device__ __forceinline__ float exp2_hw(float x) {
    float r; asm("v_exp_f32 %0, %1" : "=v"(r) : "v"(x)); return r;
}
__device__ __forceinline__ void gll16(const unsigned short* g, unsigned short* l) {
    __builtin_amdgcn_global_load_lds(
        (const __attribute__((address_space(1))) void*)g,
        (__attribute__((address_space(3))) void*)l, 16, 0, 0);
}

__global__ __launch_bounds__(256)
void fill_constf(float* __restrict__ out, long n, float v) {
    long i = (long)blockIdx.x * 256 + threadIdx.x;
    const long stride = (long)gridDim.x * 256;
    for (; i < n; i += stride) out[i] = v;
}

// fp32 -> bf16 bulk convert, 8 elems/iter.
__global__ __launch_bounds__(256)
void cvt_bf16(const float* __restrict__ src, unsigned short* __restrict__ dst, long n8) {
    long t = (long)blockIdx.x * 256 + threadIdx.x;
    const long stride = (long)gridDim.x * 256;
    for (; t < n8; t += stride) {
        const float4 a = *(const float4*)(src + t * 8);
        const float4 b = *(const float4*)(src + t * 8 + 4);
        *(uint4*)(dst + t * 8) = pk8(a, b);
    }
}
// two-tensor variant (x and qkv_w in one launch)
__global__ __launch_bounds__(256)
void cvt2_bf16(const float* __restrict__ s0, unsigned short* __restrict__ d0, long n0,
               const float* __restrict__ s1, unsigned short* __restrict__ d1, long n1) {
    long t = (long)blockIdx.x * 256 + threadIdx.x;
    const long stride = (long)gridDim.x * 256;
    for (; t < n0 + n1; t += stride) {
        const float* s; unsigned short* d; long i;
        if (t < n0) { s = s0; d = d0; i = t; } else { s = s1; d = d1; i = t - n0; }
        const float4 a = *(const float4*)(s + i * 8);
        const float4 b = *(const float4*)(s + i * 8 + 4);
        *(uint4*)(d + i * 8) = pk8(a, b);
    }
}

// C = A[M,K]·W[N,K]^T + bias, bf16 in, global_load_lds staging.
// Depth-2 software pipeline: 3 LDS buffer sets, counted s_waitcnt vmcnt(4),
// one raw s_barrier per K-step. Chunk-XOR swizzled LDS via pre-swizzled
// global source + swizzled ds_read (gll dest stays linear).
// mode 0: scatter bf16 -> q (pre-scaled by SCQ) / k (row-scatter) and V^T
// (packed 8B); mode 1: fp32 store.
__global__ __launch_bounds__(256)
void gemm_bf16(const unsigned short* __restrict__ A,
               const unsigned short* __restrict__ W,
               const float* __restrict__ bias,
               unsigned short* __restrict__ o0,
               unsigned short* __restrict__ o1,
               unsigned short* __restrict__ o2,
               float* __restrict__ of,
               int mode)
{
    __shared__ __align__(16) unsigned short lA[3][128 * 32];
    __shared__ __align__(16) unsigned short lB[3][128 * 32];
    const int tid  = threadIdx.x;
    const int lane = tid & 63, wv = tid >> 6;
    const int quad = lane >> 4, l16 = lane & 15;
    const int wm = (wv & 1) * 64, wn = (wv >> 1) * 64;

    // bijective XCD-aware block swizzle (m204)
    const int nwg = gridDim.x * gridDim.y;
    const int bid = blockIdx.y * gridDim.x + blockIdx.x;
    const int xcd = bid & 7, boff = bid >> 3;
    const int qd = nwg >> 3, rm = nwg & 7;
    const int swz = (xcd < rm ? xcd * (qd + 1) : rm * (qd + 1) + (xcd - rm) * qd) + boff;
    const int m0 = (swz / gridDim.x) * 128, n0 = (swz % gridDim.x) * 128;

    f32x4 acc[4][4] = {};

    const int srow0 = wv * 32 + (lane >> 2);
    const int srow1 = srow0 + 16;
    const int csrc  = ((lane & 3) ^ ((lane >> 3) & 3)) * 8;
    const unsigned short* pa0 = A + (long)(m0 + srow0) * HID + csrc;
    const unsigned short* pa1 = A + (long)(m0 + srow1) * HID + csrc;
    const unsigned short* pb0 = W + (long)(n0 + srow0) * HID + csrc;
    const unsigned short* pb1 = W + (long)(n0 + srow1) * HID + csrc;

    const int cq8 = (quad ^ ((l16 >> 1) & 3)) * 8;

#define STAGE_G(bufi, koff)                                        \
    do {                                                           \
        gll16(pa0 + (koff), &lA[bufi][(wv * 2 + 0) * 512]);        \
        gll16(pa1 + (koff), &lA[bufi][(wv * 2 + 1) * 512]);        \
        gll16(pb0 + (koff), &lB[bufi][(wv * 2 + 0) * 512]);        \
        gll16(pb1 + (koff), &lB[bufi][(wv * 2 + 1) * 512]);        \
    } while (0)

    STAGE_G(0, 0);
    STAGE_G(1, 32);

    int cur = 0;
    for (int k0 = 0; k0 < HID; k0 += 32) {
        if (k0 + 32 < HID) { asm volatile("s_waitcnt vmcnt(4)" ::: "memory"); }
        else               { asm volatile("s_waitcnt vmcnt(0)" ::: "memory"); }
        __builtin_amdgcn_s_barrier();
        asm volatile("" ::: "memory");

        if (k0 + 64 < HID) {
            const int nxt = cur ? cur - 1 : 2;       // (cur+2) mod 3
            STAGE_G(nxt, k0 + 64);
        }

        bf16x8 af[4], bfr[4];
#pragma unroll
        for (int mt = 0; mt < 4; mt++)
            af[mt] = *(const bf16x8*)&lA[cur][(wm + mt * 16 + l16) * 32 + cq8];
#pragma unroll
        for (int nt = 0; nt < 4; nt++)
            bfr[nt] = *(const bf16x8*)&lB[cur][(wn + nt * 16 + l16) * 32 + cq8];
#pragma unroll
        for (int mt = 0; mt < 4; mt++)
#pragma unroll
            for (int nt = 0; nt < 4; nt++)
                acc[mt][nt] = __builtin_amdgcn_mfma_f32_16x16x32_bf16(
                    af[mt], bfr[nt], acc[mt][nt], 0, 0, 0);

        cur = (cur < 2) ? cur + 1 : 0;
    }
#undef STAGE_G

    if (mode == 0) {
#pragma unroll
        for (int nt = 0; nt < 4; nt++) {
            const int n = n0 + wn + nt * 16 + l16;
            const float bv = bias[n];
            const int part = n >> 10, f = n & 1023, h = f >> 6, d = f & 63;
#pragma unroll
            for (int mt = 0; mt < 4; mt++) {
                const int mbase = m0 + wm + mt * 16 + quad * 4;
                const int b = mbase >> 11, s0 = mbase & 2047;
                const int bh = b * NH + h;
                if (part == 2) {
                    // V^T: 4 consecutive s per lane -> one packed 8B store
                    uint2 o;
                    o.x = pk2(acc[mt][nt][0] + bv, acc[mt][nt][1] + bv);
                    o.y = pk2(acc[mt][nt][2] + bv, acc[mt][nt][3] + bv);
                    *(uint2*)&o2[((long)bh * HD + d) * S_LEN + s0] = o;
                } else {
                    // q gets the softmax scale folded in (f32, single rounding)
                    unsigned short* dst = (part == 0) ? o0 : o1;
                    const float qsc = (part == 0) ? SCQ : 1.0f;
#pragma unroll
                    for (int r = 0; r < 4; r++) {
                        union { __hip_bfloat16 h; unsigned short u; } cv;
                        cv.h = __float2bfloat16((acc[mt][nt][r] + bv) * qsc);
                        dst[((long)bh * S_LEN + s0 + r) * HD + d] = cv.u;
                    }
                }
            }
        }
    } else {
#pragma unroll
        for (int nt = 0; nt < 4; nt++) {
            const int n = n0 + wn + nt * 16 + l16;
            const float bv = bias[n];
#pragma unroll
            for (int mt = 0; mt < 4; mt++) {
                const int mbase = m0 + wm + mt * 16 + quad * 4;
#pragma unroll
                for (int r = 0; r < 4; r++)
                    of[(long)(mbase + r) * HID + n] = acc[mt][nt][r] + bv;
            }
        }
    }
}

// Flash attention, S^T form, exp2 softmax. 512 threads (8 waves), q-tile 128.
// q arrives pre-scaled by SCQ; mask folded into the MFMA C-init (no per-tile
// fmaf). LDS-double-buffered K/V -> ONE lgkm-only barrier per 64-key tile
// (register prefetch of tile t+2 stays in flight across it). Defer-max
// rescale (THR=8 in log2 domain).
__global__ __launch_bounds__(512)
void attn(const unsigned short* __restrict__ q,
          const unsigned short* __restrict__ k,
          const unsigned short* __restrict__ vt_g,   // [b,h,64,S]
          const int* __restrict__ mask,
          unsigned short* __restrict__ ctx)          // [b,S,1024] bf16
{
    __shared__ __align__(16) unsigned short kt[2][64 * STK];
    __shared__ __align__(16) unsigned short vt[2][64 * STK];
    __shared__ __align__(16) __bf16 pt[8][16 * 72];
    __shared__ float mkv[2][64];

    const int tid  = threadIdx.x;
    const int lane = tid & 63, wv = tid >> 6;          // wv 0..7
    const int quad = lane >> 4, l16 = lane & 15;
    const int qt = blockIdx.x, h = blockIdx.y, b = blockIdx.z;
    const int bh = b * NH + h;

    const int sq = qt * 128 + wv * 16 + l16;
    bf16x8 qf0 = *(const bf16x8*)&q[((long)bh * S_LEN + sq) * HD + quad * 8];
    bf16x8 qf1 = *(const bf16x8*)&q[((long)bh * S_LEN + sq) * HD + 32 + quad * 8];

    float mrun = -1e30f, lrun = 0.f;
    f32x4 Of[4] = {};

    // staging: 512 threads cover 64 rows x 8 chunks, one uint4 each per matrix
    const int sr = tid >> 3, sc8 = (tid & 7) * 8;
    const unsigned short* kg = k    + ((long)bh * S_LEN + sr) * HD + sc8;
    const unsigned short* vg = vt_g + ((long)bh * HD + sr) * S_LEN + sc8;
    __bf16* ptw = pt[wv];

    // prologue: tile 0 -> buf0; tile 1 -> regs
    uint4 rk = *(const uint4*)(kg);
    uint4 rv = *(const uint4*)(vg);
    float rm = 0.f;
    if (tid < 64) rm = (mask[b * S_LEN + tid] == 0) ? -1e9f : 0.f;
    *(uint4*)&kt[0][sr * STK + sc8] = rk;
    *(uint4*)&vt[0][sr * STK + sc8] = rv;
    if (tid < 64) mkv[0][tid] = rm;
    rk = *(const uint4*)(kg + (long)64 * HD);
    rv = *(const uint4*)(vg + 64);
    if (tid < 64) rm = (mask[b * S_LEN + 64 + tid] == 0) ? -1e9f : 0.f;
    asm volatile("s_waitcnt lgkmcnt(0)" ::: "memory");
    __builtin_amdgcn_s_barrier();
    asm volatile("" ::: "memory");

    for (int k0 = 0; k0 < S_LEN; k0 += 64) {
        const int cur = (k0 >> 6) & 1;
        // write tile t+1 into the other buffer (its old contents were last
        // read in iter t-1; the end-of-(t-1) barrier makes this safe),
        // then issue tile t+2 global loads (in flight across the barrier).
        if (k0 + 64 < S_LEN) {
            *(uint4*)&kt[cur ^ 1][sr * STK + sc8] = rk;
            *(uint4*)&vt[cur ^ 1][sr * STK + sc8] = rv;
            if (tid < 64) mkv[cur ^ 1][tid] = rm;
            if (k0 + 128 < S_LEN) {
                rk = *(const uint4*)(kg + (long)(k0 + 128) * HD);
                rv = *(const uint4*)(vg + (k0 + 128));
                if (tid < 64) rm = (mask[b * S_LEN + k0 + 128 + tid] == 0) ? -1e9f : 0.f;
            }
        }

        // QK^T: mask folded into accumulator init; q pre-scaled -> st is
        // already in log2 domain, no per-element fixup.
        float st[4][4];
#pragma unroll
        for (int nt = 0; nt < 4; nt++) {
            bf16x8 k0f = *(const bf16x8*)&kt[cur][(nt * 16 + l16) * STK + quad * 8];
            bf16x8 k1f = *(const bf16x8*)&kt[cur][(nt * 16 + l16) * STK + 32 + quad * 8];
            const float4 mv = *(const float4*)&mkv[cur][nt * 16 + quad * 4];
            f32x4 s = {mv.x, mv.y, mv.z, mv.w};
            s = __builtin_amdgcn_mfma_f32_16x16x32_bf16(k0f, qf0, s, 0, 0, 0);
            s = __builtin_amdgcn_mfma_f32_16x16x32_bf16(k1f, qf1, s, 0, 0, 0);
#pragma unroll
            for (int r = 0; r < 4; r++) st[nt][r] = s[r];
        }

        // tree max over 16 in-lane values + cross-quad shuffle reduce
        float mxa[4];
#pragma unroll
        for (int nt = 0; nt < 4; nt++)
            mxa[nt] = fmaxf(fmaxf(st[nt][0], st[nt][1]), fmaxf(st[nt][2], st[nt][3]));
        float mx = fmaxf(fmaxf(mxa[0], mxa[1]), fmaxf(mxa[2], mxa[3]));
        mx = fmaxf(mx, __shfl_xor(mx, 16, 64));
        mx = fmaxf(mx, __shfl_xor(mx, 32, 64));

        // defer-max: only rescale when some q-row's max grew by > 8 (log2)
        if (!__all(mx <= mrun + 8.f)) {
            const float mn = fmaxf(mrun, mx);
            const float alpha = exp2_hw(mrun - mn);
#pragma unroll
            for (int nt = 0; nt < 4; nt++) Of[nt] *= alpha;
            lrun *= alpha;
            mrun = mn;
        }

        float pr[4][4];
#pragma unroll
        for (int nt = 0; nt < 4; nt++)
#pragma unroll
            for (int r = 0; r < 4; r++) pr[nt][r] = exp2_hw(st[nt][r] - mrun);
        float rsa[4];
#pragma unroll
        for (int nt = 0; nt < 4; nt++)
            rsa[nt] = (pr[nt][0] + pr[nt][1]) + (pr[nt][2] + pr[nt][3]);
        float rs = (rsa[0] + rsa[1]) + (rsa[2] + rsa[3]);
        rs += __shfl_xor(rs, 16, 64);
        rs += __shfl_xor(rs, 32, 64);
        lrun += rs;

#pragma unroll
        for (int nt = 0; nt < 4; nt++) {
            const unsigned long long lo = pk2(pr[nt][0], pr[nt][1]);
            const unsigned long long hi = pk2(pr[nt][2], pr[nt][3]);
            *(unsigned long long*)&ptw[l16 * 72 + nt * 16 + quad * 4] = lo | (hi << 32);
        }
        asm volatile("" ::: "memory");

#pragma unroll
        for (int ks = 0; ks < 2; ks++) {
            bf16x8 bp = *(const bf16x8*)&ptw[l16 * 72 + ks * 32 + quad * 8];
#pragma unroll
            for (int nt = 0; nt < 4; nt++) {
                bf16x8 av = *(const bf16x8*)&vt[cur][(nt * 16 + l16) * STK + ks * 32 + quad * 8];
                Of[nt] = __builtin_amdgcn_mfma_f32_16x16x32_bf16(av, bp, Of[nt], 0, 0, 0);
            }
        }

        // one barrier per tile: LDS writes of tile t+1 visible; everyone done
        // reading buf[cur] before iter t+1 overwrites it. lgkm-only (global
        // prefetch loads stay in flight).
        asm volatile("s_waitcnt lgkmcnt(0)" ::: "memory");
        __builtin_amdgcn_s_barrier();
        asm volatile("" ::: "memory");
    }

    const float inv = 1.f / lrun;
#pragma unroll
    for (int nt = 0; nt < 4; nt++) {
        uint2 o;
        o.x = pk2(Of[nt][0] * inv, Of[nt][1] * inv);
        o.y = pk2(Of[nt][2] * inv, Of[nt][3] * inv);
        *(uint2*)&ctx[((long)b * S_LEN + sq) * HID + h * HD + nt * 16 + quad * 4] = o;
    }
}

extern "C" void kernel_launch(void* const* d_in, const int* in_sizes, int n_in,
                              void* d_out, int out_size, void* d_ws, size_t ws_size,
                              hipStream_t stream) {
    float* outp = (float*)d_out;

    const float* x = nullptr; const int* mask = nullptr;
    const float* qkv_w = nullptr; const float* qkv_b = nullptr;
    const float* out_w = nullptr; const float* out_b = nullptr;
    for (int i = 0; i < n_in; i++) {
        switch (in_sizes[i]) {
            case 4194304: x     = (const float*)d_in[i]; break;
            case 4096:    mask  = (const int*)d_in[i];   break;
            case 3145728: qkv_w = (const float*)d_in[i]; break;
            case 3072:    qkv_b = (const float*)d_in[i]; break;
            case 1048576: out_w = (const float*)d_in[i]; break;
            case 1024:    out_b = (const float*)d_in[i]; break;
            default: break;
        }
    }
    if (!x || !mask || !qkv_w || !qkv_b || !out_w || !out_b) {
        fill_constf<<<256, 256, 0, stream>>>(outp, (long)out_size, 1000.0f);
        return;
    }

    const size_t per = (size_t)BATCH * NH * S_LEN * HD;   // 4,194,304
    const size_t nx  = (size_t)BATCH * S_LEN * HID;
    const size_t nqw = (size_t)3 * HID * HID;
    const size_t now = (size_t)HID * HID;
    if (ws_size < 4 * per * sizeof(unsigned short)) {
        fill_constf<<<256, 256, 0, stream>>>(outp, (long)out_size, 2000.0f);
        return;
    }

    // Aliasing discipline (no buffer read+written in the same kernel):
    //   xb  = wsc : dead after gemm1; attn overwrites with ctx
    //   qwb = d_out[0,6.3MB) : dead after gemm1; gemm2 overwrites with output
    //   owb = wsq : written AFTER attn (q dead), read only by gemm2
    unsigned short* wsq = (unsigned short*)d_ws;
    unsigned short* wsk = wsq + per;
    unsigned short* wsv = wsk + per;               // V^T [b,h,64,S]
    unsigned short* wsc = wsv + per;               // phase 1: xb; phase 2: ctx
    unsigned short* xb  = wsc;
    unsigned short* qwb = (unsigned short*)d_out;
    unsigned short* owb = wsq;

    cvt2_bf16<<<1024, 256, 0, stream>>>(x, xb, (long)(nx / 8), qkv_w, qwb, (long)(nqw / 8));
    gemm_bf16<<<dim3(3 * HID / 128, BATCH * S_LEN / 128), 256, 0, stream>>>(
        xb, qwb, qkv_b, wsq, wsk, wsv, nullptr, 0);
    attn<<<dim3(S_LEN / 128, NH, BATCH), 512, 0, stream>>>(wsq, wsk, wsv, mask, wsc);
    cvt_bf16<<<512, 256, 0, stream>>>(out_w, owb, (long)(now / 8));
    gemm_bf16<<<dim3(HID / 128, BATCH * S_LEN / 128), 256, 0, stream>>>(
        wsc, owb, out_b, nullptr, nullptr, nullptr, outp, 1);
}

// Round 3
// 225.468 us; speedup vs baseline: 1.0498x; 1.0265x over previous
//
#include <hip/hip_runtime.h>
#include <hip/hip_bf16.h>

#define S_LEN 2048
#define NH    16
#define HD    64
#define HID   1024
#define BATCH 2
#define STK   72   // kt/vt LDS stride in shorts (144B rows, 16B aligned)
#define SCQ   0.18033688f   // 0.125 * log2(e), folded into q in gemm1 epilogue

typedef __bf16 bf16x8 __attribute__((ext_vector_type(8)));
typedef float  f32x4  __attribute__((ext_vector_type(4)));

__device__ __forceinline__ unsigned int pk2(float lo, float hi) {
    union { __hip_bfloat162 h; unsigned int u; } c;
    c.h = __float22bfloat162_rn(make_float2(lo, hi));   // v_cvt_pk_bf16_f32
    return c.u;
}
__device__ __forceinline__ uint4 pk8(float4 a, float4 b) {
    uint4 o;
    o.x = pk2(a.x, a.y); o.y = pk2(a.z, a.w);
    o.z = pk2(b.x, b.y); o.w = pk2(b.z, b.w);
    return o;
}
__device__ __forceinline__ float exp2_hw(float x) {
    float r; asm("v_exp_f32 %0, %1" : "=v"(r) : "v"(x)); return r;
}
__device__ __forceinline__ void gll16(const unsigned short* g, unsigned short* l) {
    __builtin_amdgcn_global_load_lds(
        (const __attribute__((address_space(1))) void*)g,
        (__attribute__((address_space(3))) void*)l, 16, 0, 0);
}

__global__ __launch_bounds__(256)
void fill_constf(float* __restrict__ out, long n, float v) {
    long i = (long)blockIdx.x * 256 + threadIdx.x;
    const long stride = (long)gridDim.x * 256;
    for (; i < n; i += stride) out[i] = v;
}

// fp32 -> bf16 bulk convert, 8 elems/iter.
__global__ __launch_bounds__(256)
void cvt_bf16(const float* __restrict__ src, unsigned short* __restrict__ dst, long n8) {
    long t = (long)blockIdx.x * 256 + threadIdx.x;
    const long stride = (long)gridDim.x * 256;
    for (; t < n8; t += stride) {
        const float4 a = *(const float4*)(src + t * 8);
        const float4 b = *(const float4*)(src + t * 8 + 4);
        *(uint4*)(dst + t * 8) = pk8(a, b);
    }
}
// two-tensor variant (x and qkv_w in one launch)
__global__ __launch_bounds__(256)
void cvt2_bf16(const float* __restrict__ s0, unsigned short* __restrict__ d0, long n0,
               const float* __restrict__ s1, unsigned short* __restrict__ d1, long n1) {
    long t = (long)blockIdx.x * 256 + threadIdx.x;
    const long stride = (long)gridDim.x * 256;
    for (; t < n0 + n1; t += stride) {
        const float* s; unsigned short* d; long i;
        if (t < n0) { s = s0; d = d0; i = t; } else { s = s1; d = d1; i = t - n0; }
        const float4 a = *(const float4*)(s + i * 8);
        const float4 b = *(const float4*)(s + i * 8 + 4);
        *(uint4*)(d + i * 8) = pk8(a, b);
    }
}

// C = A[M,K]·W[N,K]^T + bias, bf16 in, global_load_lds staging.
// Depth-2 software pipeline: 3 LDS buffer sets, counted s_waitcnt vmcnt(4),
// one raw s_barrier per K-step. Chunk-XOR swizzled LDS via pre-swizzled
// global source + swizzled ds_read (gll dest stays linear).
// mode 0: q -> Q^T [bh][d][s] packed 8B (pre-scaled by SCQ), k -> row-scatter,
// v -> V^T [bh][d][s] packed 8B; mode 1: fp32 store.
__global__ __launch_bounds__(256)
void gemm_bf16(const unsigned short* __restrict__ A,
               const unsigned short* __restrict__ W,
               const float* __restrict__ bias,
               unsigned short* __restrict__ o0,
               unsigned short* __restrict__ o1,
               unsigned short* __restrict__ o2,
               float* __restrict__ of,
               int mode)
{
    __shared__ __align__(16) unsigned short lA[3][128 * 32];
    __shared__ __align__(16) unsigned short lB[3][128 * 32];
    const int tid  = threadIdx.x;
    const int lane = tid & 63, wv = tid >> 6;
    const int quad = lane >> 4, l16 = lane & 15;
    const int wm = (wv & 1) * 64, wn = (wv >> 1) * 64;

    // bijective XCD-aware block swizzle (m204)
    const int nwg = gridDim.x * gridDim.y;
    const int bid = blockIdx.y * gridDim.x + blockIdx.x;
    const int xcd = bid & 7, boff = bid >> 3;
    const int qd = nwg >> 3, rm = nwg & 7;
    const int swz = (xcd < rm ? xcd * (qd + 1) : rm * (qd + 1) + (xcd - rm) * qd) + boff;
    const int m0 = (swz / gridDim.x) * 128, n0 = (swz % gridDim.x) * 128;

    f32x4 acc[4][4] = {};

    const int srow0 = wv * 32 + (lane >> 2);
    const int srow1 = srow0 + 16;
    const int csrc  = ((lane & 3) ^ ((lane >> 3) & 3)) * 8;
    const unsigned short* pa0 = A + (long)(m0 + srow0) * HID + csrc;
    const unsigned short* pa1 = A + (long)(m0 + srow1) * HID + csrc;
    const unsigned short* pb0 = W + (long)(n0 + srow0) * HID + csrc;
    const unsigned short* pb1 = W + (long)(n0 + srow1) * HID + csrc;

    const int cq8 = (quad ^ ((l16 >> 1) & 3)) * 8;

#define STAGE_G(bufi, koff)                                        \
    do {                                                           \
        gll16(pa0 + (koff), &lA[bufi][(wv * 2 + 0) * 512]);        \
        gll16(pa1 + (koff), &lA[bufi][(wv * 2 + 1) * 512]);        \
        gll16(pb0 + (koff), &lB[bufi][(wv * 2 + 0) * 512]);        \
        gll16(pb1 + (koff), &lB[bufi][(wv * 2 + 1) * 512]);        \
    } while (0)

    STAGE_G(0, 0);
    STAGE_G(1, 32);

    int cur = 0;
    for (int k0 = 0; k0 < HID; k0 += 32) {
        if (k0 + 32 < HID) { asm volatile("s_waitcnt vmcnt(4)" ::: "memory"); }
        else               { asm volatile("s_waitcnt vmcnt(0)" ::: "memory"); }
        __builtin_amdgcn_s_barrier();
        asm volatile("" ::: "memory");

        if (k0 + 64 < HID) {
            const int nxt = cur ? cur - 1 : 2;       // (cur+2) mod 3
            STAGE_G(nxt, k0 + 64);
        }

        bf16x8 af[4], bfr[4];
#pragma unroll
        for (int mt = 0; mt < 4; mt++)
            af[mt] = *(const bf16x8*)&lA[cur][(wm + mt * 16 + l16) * 32 + cq8];
#pragma unroll
        for (int nt = 0; nt < 4; nt++)
            bfr[nt] = *(const bf16x8*)&lB[cur][(wn + nt * 16 + l16) * 32 + cq8];
#pragma unroll
        for (int mt = 0; mt < 4; mt++)
#pragma unroll
            for (int nt = 0; nt < 4; nt++)
                acc[mt][nt] = __builtin_amdgcn_mfma_f32_16x16x32_bf16(
                    af[mt], bfr[nt], acc[mt][nt], 0, 0, 0);

        cur = (cur < 2) ? cur + 1 : 0;
    }
#undef STAGE_G

    if (mode == 0) {
#pragma unroll
        for (int nt = 0; nt < 4; nt++) {
            const int n = n0 + wn + nt * 16 + l16;
            const float bv = bias[n];
            const int part = n >> 10, f = n & 1023, h = f >> 6, d = f & 63;
#pragma unroll
            for (int mt = 0; mt < 4; mt++) {
                const int mbase = m0 + wm + mt * 16 + quad * 4;
                const int b = mbase >> 11, s0 = mbase & 2047;
                const int bh = b * NH + h;
                if (part != 1) {
                    // Q^T / V^T: 4 consecutive s per lane -> one packed 8B store.
                    // q additionally gets the softmax scale folded in.
                    const float qsc = (part == 0) ? SCQ : 1.0f;
                    unsigned short* dst = (part == 0) ? o0 : o2;
                    uint2 o;
                    o.x = pk2((acc[mt][nt][0] + bv) * qsc, (acc[mt][nt][1] + bv) * qsc);
                    o.y = pk2((acc[mt][nt][2] + bv) * qsc, (acc[mt][nt][3] + bv) * qsc);
                    *(uint2*)&dst[((long)bh * HD + d) * S_LEN + s0] = o;
                } else {
                    // K stays row-major [bh][s][d] (row-scatter)
#pragma unroll
                    for (int r = 0; r < 4; r++) {
                        union { __hip_bfloat16 h; unsigned short u; } cv;
                        cv.h = __float2bfloat16(acc[mt][nt][r] + bv);
                        o1[((long)bh * S_LEN + s0 + r) * HD + d] = cv.u;
                    }
                }
            }
        }
    } else {
#pragma unroll
        for (int nt = 0; nt < 4; nt++) {
            const int n = n0 + wn + nt * 16 + l16;
            const float bv = bias[n];
#pragma unroll
            for (int mt = 0; mt < 4; mt++) {
                const int mbase = m0 + wm + mt * 16 + quad * 4;
#pragma unroll
                for (int r = 0; r < 4; r++)
                    of[(long)(mbase + r) * HID + n] = acc[mt][nt][r] + bv;
            }
        }
    }
}

// Flash attention, S^T form, exp2 softmax. 512 threads (8 waves), q-tile 128.
// q arrives pre-scaled AND transposed ([bh][d][s]); mask folded into the MFMA
// C-init. LDS-double-buffered K/V, ONE lgkm-only barrier per 64-key tile.
// NO per-tile cross-lane reductions: per-lane max + wave vote (defer-max,
// THR=8 in log2 domain) and per-lane partial row-sums reduced once at the end.
__global__ __launch_bounds__(512)
void attn(const unsigned short* __restrict__ q,     // Q^T [b,h,64,S], pre-scaled
          const unsigned short* __restrict__ k,     // K   [b,h,S,64]
          const unsigned short* __restrict__ vt_g,  // V^T [b,h,64,S]
          const int* __restrict__ mask,
          unsigned short* __restrict__ ctx)         // [b,S,1024] bf16
{
    __shared__ __align__(16) unsigned short kt[2][64 * STK];
    __shared__ __align__(16) unsigned short vt[2][64 * STK];
    __shared__ __align__(16) __bf16 pt[8][16 * 72];
    __shared__ float mkv[2][64];

    const int tid  = threadIdx.x;
    const int lane = tid & 63, wv = tid >> 6;          // wv 0..7
    const int quad = lane >> 4, l16 = lane & 15;
    const int qt = blockIdx.x, h = blockIdx.y, b = blockIdx.z;
    const int bh = b * NH + h;

    const int sq = qt * 128 + wv * 16 + l16;

    // gather q fragment from Q^T (16 one-time scalar loads; d varies per j)
    const unsigned short* qtg = q + (long)bh * HD * S_LEN + sq;
    union { unsigned short u[8]; bf16x8 v; } qu0, qu1;
#pragma unroll
    for (int j = 0; j < 8; j++) {
        qu0.u[j] = qtg[(long)(quad * 8 + j) * S_LEN];
        qu1.u[j] = qtg[(long)(32 + quad * 8 + j) * S_LEN];
    }
    const bf16x8 qf0 = qu0.v, qf1 = qu1.v;

    float mrun = -1e30f;
    float lsum = 0.f;            // per-lane partial row-sum (reduced at end)
    f32x4 Of[4] = {};

    // staging: 512 threads cover 64 rows x 8 chunks, one uint4 each per matrix
    const int sr = tid >> 3, sc8 = (tid & 7) * 8;
    const unsigned short* kg = k    + ((long)bh * S_LEN + sr) * HD + sc8;
    const unsigned short* vg = vt_g + ((long)bh * HD + sr) * S_LEN + sc8;
    __bf16* ptw = pt[wv];

    // prologue: tile 0 -> buf0; tile 1 -> regs
    uint4 rk = *(const uint4*)(kg);
    uint4 rv = *(const uint4*)(vg);
    float rmv = 0.f;
    if (tid < 64) rmv = (mask[b * S_LEN + tid] == 0) ? -1e9f : 0.f;
    *(uint4*)&kt[0][sr * STK + sc8] = rk;
    *(uint4*)&vt[0][sr * STK + sc8] = rv;
    if (tid < 64) mkv[0][tid] = rmv;
    rk = *(const uint4*)(kg + (long)64 * HD);
    rv = *(const uint4*)(vg + 64);
    if (tid < 64) rmv = (mask[b * S_LEN + 64 + tid] == 0) ? -1e9f : 0.f;
    asm volatile("s_waitcnt lgkmcnt(0)" ::: "memory");
    __builtin_amdgcn_s_barrier();
    asm volatile("" ::: "memory");

    for (int k0 = 0; k0 < S_LEN; k0 += 64) {
        const int cur = (k0 >> 6) & 1;
        // write tile t+1 into the other buffer; issue tile t+2 global loads
        // (they stay in flight across the barrier).
        if (k0 + 64 < S_LEN) {
            *(uint4*)&kt[cur ^ 1][sr * STK + sc8] = rk;
            *(uint4*)&vt[cur ^ 1][sr * STK + sc8] = rv;
            if (tid < 64) mkv[cur ^ 1][tid] = rmv;
            if (k0 + 128 < S_LEN) {
                rk = *(const uint4*)(kg + (long)(k0 + 128) * HD);
                rv = *(const uint4*)(vg + (k0 + 128));
                if (tid < 64) rmv = (mask[b * S_LEN + k0 + 128 + tid] == 0) ? -1e9f : 0.f;
            }
        }

        // QK^T: mask folded into accumulator init; q pre-scaled -> st is
        // already in log2 domain.
        float st[4][4];
        __builtin_amdgcn_s_setprio(1);
#pragma unroll
        for (int nt = 0; nt < 4; nt++) {
            bf16x8 k0f = *(const bf16x8*)&kt[cur][(nt * 16 + l16) * STK + quad * 8];
            bf16x8 k1f = *(const bf16x8*)&kt[cur][(nt * 16 + l16) * STK + 32 + quad * 8];
            const float4 mv = *(const float4*)&mkv[cur][nt * 16 + quad * 4];
            f32x4 s = {mv.x, mv.y, mv.z, mv.w};
            s = __builtin_amdgcn_mfma_f32_16x16x32_bf16(k0f, qf0, s, 0, 0, 0);
            s = __builtin_amdgcn_mfma_f32_16x16x32_bf16(k1f, qf1, s, 0, 0, 0);
#pragma unroll
            for (int r = 0; r < 4; r++) st[nt][r] = s[r];
        }
        __builtin_amdgcn_s_setprio(0);

        // per-lane max tree (NO cross-lane ops on the common path)
        float mxa[4];
#pragma unroll
        for (int nt = 0; nt < 4; nt++)
            mxa[nt] = fmaxf(fmaxf(st[nt][0], st[nt][1]), fmaxf(st[nt][2], st[nt][3]));
        const float pmax = fmaxf(fmaxf(mxa[0], mxa[1]), fmaxf(mxa[2], mxa[3]));

        // defer-max: rescale only when some lane's max grew by > 8 (log2).
        // In-branch cross-lane max makes mrun row-consistent again.
        if (__any(pmax > mrun + 8.f)) {
            float mx = fmaxf(pmax, __shfl_xor(pmax, 16, 64));
            mx = fmaxf(mx, __shfl_xor(mx, 32, 64));
            const float mn = fmaxf(mrun, mx);
            const float alpha = exp2_hw(mrun - mn);
#pragma unroll
            for (int nt = 0; nt < 4; nt++) Of[nt] *= alpha;
            lsum *= alpha;
            mrun = mn;
        }

        float pr[4][4];
#pragma unroll
        for (int nt = 0; nt < 4; nt++)
#pragma unroll
            for (int r = 0; r < 4; r++) pr[nt][r] = exp2_hw(st[nt][r] - mrun);
        // per-lane partial sum only; cross-lane reduce deferred to epilogue
        float rsa[4];
#pragma unroll
        for (int nt = 0; nt < 4; nt++)
            rsa[nt] = (pr[nt][0] + pr[nt][1]) + (pr[nt][2] + pr[nt][3]);
        lsum += (rsa[0] + rsa[1]) + (rsa[2] + rsa[3]);

#pragma unroll
        for (int nt = 0; nt < 4; nt++) {
            const unsigned long long lo = pk2(pr[nt][0], pr[nt][1]);
            const unsigned long long hi = pk2(pr[nt][2], pr[nt][3]);
            *(unsigned long long*)&ptw[l16 * 72 + nt * 16 + quad * 4] = lo | (hi << 32);
        }
        asm volatile("" ::: "memory");

        __builtin_amdgcn_s_setprio(1);
#pragma unroll
        for (int ks = 0; ks < 2; ks++) {
            bf16x8 bp = *(const bf16x8*)&ptw[l16 * 72 + ks * 32 + quad * 8];
#pragma unroll
            for (int nt = 0; nt < 4; nt++) {
                bf16x8 av = *(const bf16x8*)&vt[cur][(nt * 16 + l16) * STK + ks * 32 + quad * 8];
                Of[nt] = __builtin_amdgcn_mfma_f32_16x16x32_bf16(av, bp, Of[nt], 0, 0, 0);
            }
        }
        __builtin_amdgcn_s_setprio(0);

        // one barrier per tile: LDS writes of tile t+1 visible; everyone done
        // reading buf[cur] before iter t+1 overwrites it. lgkm-only (global
        // prefetch loads stay in flight).
        asm volatile("s_waitcnt lgkmcnt(0)" ::: "memory");
        __builtin_amdgcn_s_barrier();
        asm volatile("" ::: "memory");
    }

    // single cross-lane reduction of the row-sum (quads l16, +16, +32, +48)
    float lt = lsum + __shfl_xor(lsum, 16, 64);
    lt += __shfl_xor(lt, 32, 64);
    const float inv = 1.f / lt;
#pragma unroll
    for (int nt = 0; nt < 4; nt++) {
        uint2 o;
        o.x = pk2(Of[nt][0] * inv, Of[nt][1] * inv);
        o.y = pk2(Of[nt][2] * inv, Of[nt][3] * inv);
        *(uint2*)&ctx[((long)b * S_LEN + sq) * HID + h * HD + nt * 16 + quad * 4] = o;
    }
}

extern "C" void kernel_launch(void* const* d_in, const int* in_sizes, int n_in,
                              void* d_out, int out_size, void* d_ws, size_t ws_size,
                              hipStream_t stream) {
    float* outp = (float*)d_out;

    const float* x = nullptr; const int* mask = nullptr;
    const float* qkv_w = nullptr; const float* qkv_b = nullptr;
    const float* out_w = nullptr; const float* out_b = nullptr;
    for (int i = 0; i < n_in; i++) {
        switch (in_sizes[i]) {
            case 4194304: x     = (const float*)d_in[i]; break;
            case 4096:    mask  = (const int*)d_in[i];   break;
            case 3145728: qkv_w = (const float*)d_in[i]; break;
            case 3072:    qkv_b = (const float*)d_in[i]; break;
            case 1048576: out_w = (const float*)d_in[i]; break;
            case 1024:    out_b = (const float*)d_in[i]; break;
            default: break;
        }
    }
    if (!x || !mask || !qkv_w || !qkv_b || !out_w || !out_b) {
        fill_constf<<<256, 256, 0, stream>>>(outp, (long)out_size, 1000.0f);
        return;
    }

    const size_t per = (size_t)BATCH * NH * S_LEN * HD;   // 4,194,304
    const size_t nx  = (size_t)BATCH * S_LEN * HID;
    const size_t nqw = (size_t)3 * HID * HID;
    const size_t now = (size_t)HID * HID;
    if (ws_size < 4 * per * sizeof(unsigned short)) {
        fill_constf<<<256, 256, 0, stream>>>(outp, (long)out_size, 2000.0f);
        return;
    }

    // Aliasing discipline (no buffer read+written in the same kernel):
    //   xb  = wsc : dead after gemm1; attn overwrites with ctx
    //   qwb = d_out[0,6.3MB) : dead after gemm1; gemm2 overwrites with output
    //   owb = wsq : written AFTER attn (q dead), read only by gemm2
    unsigned short* wsq = (unsigned short*)d_ws;
    unsigned short* wsk = wsq + per;
    unsigned short* wsv = wsk + per;               // V^T [b,h,64,S]
    unsigned short* wsc = wsv + per;               // phase 1: xb; phase 2: ctx
    unsigned short* xb  = wsc;
    unsigned short* qwb = (unsigned short*)d_out;
    unsigned short* owb = wsq;

    cvt2_bf16<<<1024, 256, 0, stream>>>(x, xb, (long)(nx / 8), qkv_w, qwb, (long)(nqw / 8));
    gemm_bf16<<<dim3(3 * HID / 128, BATCH * S_LEN / 128), 256, 0, stream>>>(
        xb, qwb, qkv_b, wsq, wsk, wsv, nullptr, 0);
    attn<<<dim3(S_LEN / 128, NH, BATCH), 512, 0, stream>>>(wsq, wsk, wsv, mask, wsc);
    cvt_bf16<<<512, 256, 0, stream>>>(out_w, owb, (long)(now / 8));
    gemm_bf16<<<dim3(HID / 128, BATCH * S_LEN / 128), 256, 0, stream>>>(
        wsc, owb, out_b, nullptr, nullptr, nullptr, outp, 1);
}